// Round 6
// baseline (1011.479 us; speedup 1.0000x reference)
//
#include <hip/hip_runtime.h>
#include <math.h>

#define PI_F 3.14159265358979323846f

typedef short bf16x8 __attribute__((ext_vector_type(8)));
typedef float f32x4  __attribute__((ext_vector_type(4)));

__device__ __forceinline__ short f2bf(float f) {
    union { float f; unsigned u; } v; v.f = f;
    unsigned r = v.u + 0x7fffu + ((v.u >> 16) & 1u);
    return (short)(r >> 16);
}

// ---------------- prep kernels ----------------

// s1in: [b][g][1024][8] bf16: ch 0..3 = x group, 4..7 = 0
__global__ __launch_bounds__(256) void prep_s1in(const float* __restrict__ x, short* __restrict__ dst) {
    int idx = blockIdx.x * 256 + threadIdx.x;
    if (idx >= 64 * 1024) return;
    int px = idx & 1023;
    int g  = (idx >> 10) & 3;
    int b  = idx >> 12;
    short v8[8];
    #pragma unroll
    for (int j = 0; j < 8; ++j) {
        float f = (j < 4) ? x[((b * 16 + g * 4 + j) << 10) + px] : 0.f;
        v8[j] = f2bf(f);
    }
    *(int4*)(dst + (size_t)idx * 8) = *(const int4*)v8;
}

// write x-group (4 ch) + 4 zeros at channel CH0 of a [pair][1024][CHS] bf16 buffer
__global__ __launch_bounds__(256) void prep_sx(const float* __restrict__ x, short* __restrict__ dst,
                                               int CHS, int CH0) {
    int idx = blockIdx.x * 256 + threadIdx.x;          // (pair, px)
    if (idx >= 128 * 1024) return;
    int px = idx & 1023, pair = idx >> 10;
    int i = pair >> 4, b = pair & 15, g = i >> 1;
    short v8[8];
    #pragma unroll
    for (int j = 0; j < 8; ++j) {
        float f = (j < 4) ? x[((b * 16 + g * 4 + j) << 10) + px] : 0.f;
        v8[j] = f2bf(f);
    }
    *(int4*)(dst + (size_t)idx * CHS + CH0) = *(const int4*)v8;
}

// weights [8][COUT][CINR][KS*KS] fp32 -> dense-K layout [8][kh][chunk][COUT][32] bf16
template<int KS, int CHS, int CINR, int COUT, int NCH>
__global__ __launch_bounds__(256) void wprep_d(const float* __restrict__ w, short* __restrict__ Bw) {
    constexpr int TOTAL = 8 * KS * NCH * COUT * 4;
    int idx = blockIdx.x * 256 + threadIdx.x;
    if (idx >= TOTAL) return;
    int kb = idx & 3;
    int r  = idx >> 2;
    int n  = r % COUT;  r /= COUT;
    int c  = r % NCH;   r /= NCH;
    int kh = r % KS;
    int br = r / KS;
    short v8[8];
    #pragma unroll
    for (int j = 0; j < 8; ++j) {
        int k   = c * 32 + kb * 8 + j;
        int kwc = k / CHS;
        int ch  = k - kwc * CHS;
        float f = (kwc < KS && ch < CINR)
                ? w[(((size_t)br * COUT + n) * CINR + ch) * (KS * KS) + kh * KS + kwc] : 0.f;
        v8[j] = f2bf(f);
    }
    *(int4*)(Bw + (size_t)idx * 8) = *(const int4*)v8;
}

// ---------------- MFMA conv stage (dense-K, B from global, reg-pipelined) ----------------
// 512 thr = 8 waves (WM=4 x WN=2). Per-wave output: 32 px x 64 cout (acc = 2x4 frags = 32 regs).
// A: [ROWS=4][TCX][CHS] bf16 in LDS, restaged per kh (2 barriers/kh).
// B: frag-layout global stream, explicit even/odd register prefetch (never drains in-kh).
template<int KS, int CHS, int COUT, int NCOH, int CHS_OUT, int FOFF, bool S1SRC>
__global__ __launch_bounds__(512, 4) void conv_mfma(
    const short* __restrict__ sIn,
    short* __restrict__ sOut,
    const short* __restrict__ Bw,      // [8][KS][NCH][COUT][32] bf16
    const float* __restrict__ bias,    // [8][COUT]
    float* __restrict__ sums)          // [16][3584][2] fp32
{
    constexpr int PAD    = KS / 2;
    constexpr int NCH    = (KS * CHS + 31) / 32;        // K-chunks per kh-row
    constexpr int TCX    = 32 + (NCH * 32 - 1) / CHS;   // staged cols per row
    constexpr int ROWS   = 4;                           // image rows per block (1 per wm)
    constexpr int CO_BLK = COUT / NCOH;                 // couts per block
    constexpr int NFN    = CO_BLK / 32;                 // B frags per wave (WN=2)
    constexpr int CPP    = CHS / 8;                     // 16B chunks per pixel
    constexpr int TCHK   = ROWS * TCX * CPP;            // 16B chunks in A tile
    constexpr int CHUNKB = COUT * 32;                   // shorts per chunk panel
    static_assert(NCH == 1 || (NCH % 2) == 0, "NCH must be 1 or even");

    __shared__ int4 AtileV[(ROWS * TCX * CHS) / 8];
    short* Atile = (short*)AtileV;

    const int t    = threadIdx.x;
    const int lane = t & 63, w = t >> 6;
    const int wm = w >> 1, wn = w & 1;                  // 4 x 2
    const int lm = lane & 15, kb = lane >> 4;

    const int bid = blockIdx.x;
    const int i    = bid & 7;          // branch (-> XCD locality for B stream)
    const int b    = (bid >> 3) & 15;  // image
    const int rest = bid >> 7;
    const int mt   = rest & 7;         // m-tile (4 rows each)
    const int coh  = rest >> 3;        // cout-half (conv7 only)
    const int r0 = mt * ROWS;

    const int pairPx = (i * 16 + b) << 10;
    const int srcPx  = S1SRC ? ((b * 4 + (i >> 1)) << 10) : pairPx;

    // A-frag bases (shorts): wave's image row = wm, col-half = fm
    int aBase[2];
    #pragma unroll
    for (int fm = 0; fm < 2; ++fm)
        aBase[fm] = (wm * TCX + fm * 16 + lm) * CHS + kb * 8;

    // B-frag indices/offsets
    int nIdx[NFN], nOff[NFN];
    #pragma unroll
    for (int fn = 0; fn < NFN; ++fn) {
        nIdx[fn] = coh * CO_BLK + wn * (CO_BLK / 2) + fn * 16 + lm;
        nOff[fn] = nIdx[fn] * 32 + kb * 8;
    }

    f32x4 acc[2][NFN];
    #pragma unroll
    for (int fm = 0; fm < 2; ++fm)
        #pragma unroll
        for (int fn = 0; fn < NFN; ++fn)
            acc[fm][fn] = (f32x4){0.f, 0.f, 0.f, 0.f};

    const short* Bp = Bw + (size_t)i * KS * NCH * CHUNKB;  // flat over (kh, chunk)
    bf16x8 b0[NFN], b1[NFN];

    for (int kh = 0; kh < KS; ++kh) {
        __syncthreads();
        // issue this kh's chunk-0 B loads early (independent of LDS) — hide under staging
        #pragma unroll
        for (int fn = 0; fn < NFN; ++fn)
            b0[fn] = *(const bf16x8*)(Bp + nOff[fn]);

        // stage A rows for this kh
        for (int e = t; e < TCHK; e += 512) {
            int kc = e % CPP, r = e / CPP;
            int tc = r % TCX, tr = r / TCX;
            int rin = r0 + kh - PAD + tr, cin = tc - PAD;
            int4 v = {0, 0, 0, 0};
            if (rin >= 0 && rin < 32 && cin >= 0 && cin < 32)
                v = *(const int4*)(sIn + (size_t)(srcPx + rin * 32 + cin) * CHS + kc * 8);
            *(int4*)(Atile + (size_t)e * 8) = v;
        }
        __syncthreads();

        if constexpr (NCH == 1) {
            __builtin_amdgcn_s_setprio(1);
            bf16x8 af0 = *(const bf16x8*)(Atile + aBase[0]);
            bf16x8 af1 = *(const bf16x8*)(Atile + aBase[1]);
            #pragma unroll
            for (int fn = 0; fn < NFN; ++fn)
                acc[0][fn] = __builtin_amdgcn_mfma_f32_16x16x32_bf16(af0, b0[fn], acc[0][fn], 0, 0, 0);
            #pragma unroll
            for (int fn = 0; fn < NFN; ++fn)
                acc[1][fn] = __builtin_amdgcn_mfma_f32_16x16x32_bf16(af1, b0[fn], acc[1][fn], 0, 0, 0);
            __builtin_amdgcn_s_setprio(0);
            Bp += CHUNKB;
        } else {
            #pragma unroll 1
            for (int c = 0; c < NCH; c += 2) {
                // prefetch odd chunk
                #pragma unroll
                for (int fn = 0; fn < NFN; ++fn)
                    b1[fn] = *(const bf16x8*)(Bp + (size_t)(c + 1) * CHUNKB + nOff[fn]);
                // even MFMA cluster
                {
                    __builtin_amdgcn_s_setprio(1);
                    bf16x8 af0 = *(const bf16x8*)(Atile + aBase[0] + c * 32);
                    bf16x8 af1 = *(const bf16x8*)(Atile + aBase[1] + c * 32);
                    #pragma unroll
                    for (int fn = 0; fn < NFN; ++fn)
                        acc[0][fn] = __builtin_amdgcn_mfma_f32_16x16x32_bf16(af0, b0[fn], acc[0][fn], 0, 0, 0);
                    #pragma unroll
                    for (int fn = 0; fn < NFN; ++fn)
                        acc[1][fn] = __builtin_amdgcn_mfma_f32_16x16x32_bf16(af1, b0[fn], acc[1][fn], 0, 0, 0);
                    __builtin_amdgcn_s_setprio(0);
                }
                // prefetch next even chunk
                if (c + 2 < NCH) {
                    #pragma unroll
                    for (int fn = 0; fn < NFN; ++fn)
                        b0[fn] = *(const bf16x8*)(Bp + (size_t)(c + 2) * CHUNKB + nOff[fn]);
                }
                // odd MFMA cluster
                {
                    __builtin_amdgcn_s_setprio(1);
                    bf16x8 af0 = *(const bf16x8*)(Atile + aBase[0] + (c + 1) * 32);
                    bf16x8 af1 = *(const bf16x8*)(Atile + aBase[1] + (c + 1) * 32);
                    #pragma unroll
                    for (int fn = 0; fn < NFN; ++fn)
                        acc[0][fn] = __builtin_amdgcn_mfma_f32_16x16x32_bf16(af0, b1[fn], acc[0][fn], 0, 0, 0);
                    #pragma unroll
                    for (int fn = 0; fn < NFN; ++fn)
                        acc[1][fn] = __builtin_amdgcn_mfma_f32_16x16x32_bf16(af1, b1[fn], acc[1][fn], 0, 0, 0);
                    __builtin_amdgcn_s_setprio(0);
                }
            }
            Bp += (size_t)NCH * CHUNKB;
        }
    }

    // ---------------- epilogue: bias + relu + store + DCT reduction ----------------
    float cwv[2][4];
    #pragma unroll
    for (int fm = 0; fm < 2; ++fm)
        #pragma unroll
        for (int r = 0; r < 4; ++r)
            cwv[fm][r] = cosf(PI_F * (fm * 16 + kb * 4 + r + 0.5f) / 32.f);

    #pragma unroll
    for (int fn = 0; fn < NFN; ++fn) {
        int n = nIdx[fn];
        float bv = bias[i * COUT + n];
        float s0 = 0.f, s1 = 0.f;
        #pragma unroll
        for (int fm = 0; fm < 2; ++fm) {
            #pragma unroll
            for (int r = 0; r < 4; ++r) {
                float v = fmaxf(acc[fm][fn][r] + bv, 0.f);
                if constexpr (CHS_OUT > 0) {
                    int col = fm * 16 + kb * 4 + r;
                    int R = r0 + wm;
                    sOut[(size_t)(pairPx + R * 32 + col) * CHS_OUT + n] = f2bf(v);
                }
                s0 += v;
                s1 += v * cwv[fm][r];
            }
        }
        s0 += __shfl_xor(s0, 16); s1 += __shfl_xor(s1, 16);
        s0 += __shfl_xor(s0, 32); s1 += __shfl_xor(s1, 32);
        if (kb == 0) {
            int ch = i * 448 + FOFF + n;
            atomicAdd(&sums[((size_t)b * 3584 + ch) * 2 + 0], s0);
            atomicAdd(&sums[((size_t)b * 3584 + ch) * 2 + 1], s1);
        }
    }
}

// ---------------- head: LN stats (16 blocks) + parallel GEMV (960 blocks) ----------------
__global__ __launch_bounds__(256) void ln_stats(const float* __restrict__ sums,
                                                float* __restrict__ stats) {
    __shared__ float red[8];
    const int b = blockIdx.x;
    const int t = threadIdx.x, lane = t & 63, wv = t >> 6;
    const float* S = sums + (size_t)b * 7168;
    float ls = 0.f, lq = 0.f;
    for (int f = t; f < 7168; f += 256) { float v = S[f]; ls += v; lq += v * v; }
    for (int m = 1; m < 64; m <<= 1) { ls += __shfl_xor(ls, m); lq += __shfl_xor(lq, m); }
    if (lane == 0) { red[wv] = ls; red[4 + wv] = lq; }
    __syncthreads();
    if (t == 0) {
        float ts = red[0] + red[1] + red[2] + red[3];
        float tq = red[4] + red[5] + red[6] + red[7];
        float mu  = ts * (1.f / 7168.f);
        float var = tq * (1.f / 7168.f) - mu * mu;
        stats[b * 2 + 0] = mu;
        stats[b * 2 + 1] = rsqrtf(var + 1e-5f);
    }
}

__global__ __launch_bounds__(256) void head_gemv(
    const float* __restrict__ sums,   // [16][7168]
    const float* __restrict__ stats,  // [16][2]
    const float* __restrict__ Wg, const float* __restrict__ bg,
    const float* __restrict__ gamma, const float* __restrict__ beta,
    const float* __restrict__ Wd, const float* __restrict__ bd,
    float* __restrict__ out)          // [960 gap][960 dct]
{
    __shared__ float red[8];
    const int n = blockIdx.x % 60;
    const int b = blockIdx.x / 60;
    const int t = threadIdx.x, lane = t & 63, wv = t >> 6;
    const float* S  = sums + (size_t)b * 7168;
    const float mu  = stats[b * 2 + 0];
    const float inv = stats[b * 2 + 1];

    const float* wd = Wd + (size_t)n * 7168;
    float accd = 0.f;
    for (int f = t; f < 7168; f += 256) {
        float v = (S[f] - mu) * inv * gamma[f] + beta[f];
        accd = fmaf(v, wd[f], accd);
    }
    const float* wg = Wg + (size_t)n * 3584;
    float accg = 0.f;
    for (int ch = t; ch < 3584; ch += 256)
        accg = fmaf(S[2 * ch], wg[ch], accg);

    for (int m = 1; m < 64; m <<= 1) { accg += __shfl_xor(accg, m); accd += __shfl_xor(accd, m); }
    if (lane == 0) { red[wv] = accg; red[4 + wv] = accd; }
    __syncthreads();
    if (t == 0) {
        float g = red[0] + red[1] + red[2] + red[3];
        float d = red[4] + red[5] + red[6] + red[7];
        out[b * 60 + n]       = g * (1.f / 1024.f) + bg[n];
        out[960 + b * 60 + n] = d + bd[n];
    }
}

extern "C" void kernel_launch(void* const* d_in, const int* in_sizes, int n_in,
                              void* d_out, int out_size, void* d_ws, size_t ws_size,
                              hipStream_t stream)
{
    const float* x     = (const float*)d_in[0];
    const float* w3    = (const float*)d_in[1];
    const float* b3    = (const float*)d_in[2];
    const float* w5    = (const float*)d_in[3];
    const float* b5    = (const float*)d_in[4];
    const float* w7    = (const float*)d_in[5];
    const float* b7    = (const float*)d_in[6];
    const float* Wg    = (const float*)d_in[7];
    const float* bg    = (const float*)d_in[8];
    const float* gamma = (const float*)d_in[9];
    const float* beta  = (const float*)d_in[10];
    const float* Wd    = (const float*)d_in[11];
    const float* bd    = (const float*)d_in[12];
    float* out = (float*)d_out;

    // workspace layout (bytes)
    char* p = (char*)d_ws;
    float* sums  = (float*)p;             p += 458752;      // 16*3584*2 f32
    float* stats = (float*)p;             p += 128;         // 16*2 f32
    short* s1in = (short*)p;              p += 1048576;     // [64][1024][8]    bf16
    short* s2in = (short*)p;              p += 18874368;    // [128][1024][72]  bf16
    short* s3in = (short*)p;              p += 35651584;    // [128][1024][136] bf16
    short* Bw3  = (short*)p;              p += 98304;       // [8][3][1][64][32]
    short* Bw5  = (short*)p;              p += 3932160;     // [8][5][12][128][32]
    short* Bw7  = (short*)p;              p += 27525120;    // [8][7][30][256][32]

    hipMemsetAsync(sums, 0, 458752, stream);
    prep_s1in<<<dim3(256), dim3(256), 0, stream>>>(x, s1in);
    prep_sx<<<dim3(512), dim3(256), 0, stream>>>(x, s2in, 72, 64);
    prep_sx<<<dim3(512), dim3(256), 0, stream>>>(x, s3in, 136, 128);
    wprep_d<3, 8, 4, 64, 1><<<dim3(24), dim3(256), 0, stream>>>(w3, Bw3);
    wprep_d<5, 72, 68, 128, 12><<<dim3(960), dim3(256), 0, stream>>>(w5, Bw5);
    wprep_d<7, 136, 132, 256, 30><<<dim3(6720), dim3(256), 0, stream>>>(w7, Bw7);

    conv_mfma<3, 8, 64, 1, 72, 0, true><<<dim3(1024), dim3(512), 0, stream>>>(s1in, s2in, Bw3, b3, sums);
    conv_mfma<5, 72, 128, 1, 136, 64, false><<<dim3(1024), dim3(512), 0, stream>>>(s2in, s3in, Bw5, b5, sums);
    conv_mfma<7, 136, 256, 2, 0, 192, false><<<dim3(2048), dim3(512), 0, stream>>>(s3in, nullptr, Bw7, b7, sums);

    ln_stats<<<dim3(16), dim3(256), 0, stream>>>(sums, stats);
    head_gemv<<<dim3(960), dim3(256), 0, stream>>>(sums, stats, Wg, bg, gamma, beta, Wd, bd, out);
}

// Round 7
// 492.979 us; speedup vs baseline: 2.0518x; 2.0518x over previous
//
#include <hip/hip_runtime.h>
#include <math.h>

#define PI_F 3.14159265358979323846f

typedef short bf16x8 __attribute__((ext_vector_type(8)));
typedef float f32x4  __attribute__((ext_vector_type(4)));

__device__ __forceinline__ short f2bf(float f) {
    union { float f; unsigned u; } v; v.f = f;
    unsigned r = v.u + 0x7fffu + ((v.u >> 16) & 1u);
    return (short)(r >> 16);
}

// ---------------- prep kernels ----------------

// s1in: [b][g][1024][8] bf16: ch 0..3 = x group, 4..7 = 0
__global__ __launch_bounds__(256) void prep_s1in(const float* __restrict__ x, short* __restrict__ dst) {
    int idx = blockIdx.x * 256 + threadIdx.x;
    if (idx >= 64 * 1024) return;
    int px = idx & 1023;
    int g  = (idx >> 10) & 3;
    int b  = idx >> 12;
    short v8[8];
    #pragma unroll
    for (int j = 0; j < 8; ++j) {
        float f = (j < 4) ? x[((b * 16 + g * 4 + j) << 10) + px] : 0.f;
        v8[j] = f2bf(f);
    }
    *(int4*)(dst + (size_t)idx * 8) = *(const int4*)v8;
}

// write x-group (4 ch) + 4 zeros at channel CH0 of a [pair][1024][CHS] bf16 buffer
__global__ __launch_bounds__(256) void prep_sx(const float* __restrict__ x, short* __restrict__ dst,
                                               int CHS, int CH0) {
    int idx = blockIdx.x * 256 + threadIdx.x;          // (pair, px)
    if (idx >= 128 * 1024) return;
    int px = idx & 1023, pair = idx >> 10;
    int i = pair >> 4, b = pair & 15, g = i >> 1;
    short v8[8];
    #pragma unroll
    for (int j = 0; j < 8; ++j) {
        float f = (j < 4) ? x[((b * 16 + g * 4 + j) << 10) + px] : 0.f;
        v8[j] = f2bf(f);
    }
    *(int4*)(dst + (size_t)idx * CHS + CH0) = *(const int4*)v8;
}

// weights [8][COUT][CINR][KS*KS] fp32 -> dense-K layout [8][kh][chunk][COUT][32] bf16
template<int KS, int CHS, int CINR, int COUT, int NCH>
__global__ __launch_bounds__(256) void wprep_d(const float* __restrict__ w, short* __restrict__ Bw) {
    constexpr int TOTAL = 8 * KS * NCH * COUT * 4;
    int idx = blockIdx.x * 256 + threadIdx.x;
    if (idx >= TOTAL) return;
    int kb = idx & 3;
    int r  = idx >> 2;
    int n  = r % COUT;  r /= COUT;
    int c  = r % NCH;   r /= NCH;
    int kh = r % KS;
    int br = r / KS;
    short v8[8];
    #pragma unroll
    for (int j = 0; j < 8; ++j) {
        int k   = c * 32 + kb * 8 + j;
        int kwc = k / CHS;
        int ch  = k - kwc * CHS;
        float f = (kwc < KS && ch < CINR)
                ? w[(((size_t)br * COUT + n) * CINR + ch) * (KS * KS) + kh * KS + kwc] : 0.f;
        v8[j] = f2bf(f);
    }
    *(int4*)(Bw + (size_t)idx * 8) = *(const int4*)v8;
}

// ---------------- HK-regime MFMA conv ----------------
// 1 block/CU: 512 thr = 8 waves (2 wm x 4 wn). Per-wave tile: 128 px x COUT/4.
// acc[8][NFN] 16x16 frags. A: 9-slot circular input-row buffer in LDS (1 new row
// per kh, issue-early/write-late, 1 barrier/kh). B: frag-layout global stream
// (XCD-local), flat even/odd register prefetch across (kh,chunk).
template<int KS, int CHS, int COUT, int CHS_OUT, int FOFF, bool S1SRC>
__global__ __launch_bounds__(512, 2) void conv_hk(
    const short* __restrict__ sIn,
    short* __restrict__ sOut,
    const short* __restrict__ Bw,      // [8][KS][NCH][COUT][32] bf16
    const float* __restrict__ bias,    // [8][COUT]
    float* __restrict__ sums)          // [16][3584][2] fp32
{
    constexpr int PAD    = KS / 2;
    constexpr int NCH    = (KS * CHS + 31) / 32;        // K-chunks per kh-row
    constexpr int TCX    = 32 + (NCH * 32 - 1) / CHS;   // staged cols per row
    constexpr int NSLOT  = 9;
    constexpr int NFN    = COUT / 64;                   // B frags per wave
    constexpr int CPP    = CHS / 8;                     // 16B chunks per pixel
    constexpr int RCHK   = TCX * CPP;                   // 16B chunks per staged row
    constexpr int CHUNKB = COUT * 32;                   // shorts per chunk panel
    static_assert(NCH == 1 || (NCH % 2) == 0, "NCH must be 1 or even");

    __shared__ int4 AtileV[(NSLOT * TCX * CHS) / 8];
    short* Atile = (short*)AtileV;

    const int t    = threadIdx.x;
    const int lane = t & 63, w = t >> 6;
    const int wm = w >> 2, wn = w & 3;                  // 2 x 4
    const int lm = lane & 15, kb = lane >> 4;

    const int bid = blockIdx.x;
    const int i  = bid & 7;            // branch -> XCD-local B stream
    const int b  = (bid >> 3) & 15;    // image
    const int mt = bid >> 7;           // m-tile (8 rows)
    const int r0 = mt * 8;

    const int pairPx = (i * 16 + b) << 10;
    const int srcPx  = S1SRC ? ((b * 4 + (i >> 1)) << 10) : pairPx;

    // B-frag indices/offsets
    int nIdx[NFN], nOff[NFN];
    #pragma unroll
    for (int fn = 0; fn < NFN; ++fn) {
        nIdx[fn] = wn * (COUT / 4) + fn * 16 + lm;
        nOff[fn] = nIdx[fn] * 32 + kb * 8;
    }

    f32x4 acc[8][NFN];
    #pragma unroll
    for (int fm = 0; fm < 8; ++fm)
        #pragma unroll
        for (int fn = 0; fn < NFN; ++fn)
            acc[fm][fn] = (f32x4){0.f, 0.f, 0.f, 0.f};

    const short* Bp = Bw + (size_t)i * KS * NCH * CHUNKB;  // flat over (kh, chunk)
    bf16x8 b0[NFN], b1[NFN];
    #pragma unroll
    for (int fn = 0; fn < NFN; ++fn)
        b0[fn] = *(const bf16x8*)(Bp + nOff[fn]);           // chunk 0 prefetch

    // prologue: stage rows j = 0..8 (input rows r0-PAD+j) into slots 0..8
    for (int e = t; e < 9 * RCHK; e += 512) {
        int j  = e / RCHK, e2 = e - j * RCHK;
        int tc = e2 / CPP, kc = e2 - tc * CPP;
        int rin = r0 - PAD + j, cin = tc - PAD;
        int4 v = {0, 0, 0, 0};
        if (rin >= 0 && rin < 32 && cin >= 0 && cin < 32)
            v = *(const int4*)(sIn + (size_t)(srcPx + rin * 32 + cin) * CHS + kc * 8);
        *(int4*)(Atile + (j * TCX + tc) * CHS + kc * 8) = v;
    }
    __syncthreads();

    for (int kh = 0; kh < KS; ++kh) {
        // per-kh A-frag bases (circular slots)
        int aB[8];
        #pragma unroll
        for (int fm = 0; fm < 8; ++fm) {
            int slot = kh + wm * 4 + (fm >> 1);
            if (slot >= NSLOT) slot -= NSLOT;
            aB[fm] = (slot * TCX + (fm & 1) * 16 + lm) * CHS + kb * 8;
        }

        // issue-early: the one new row (j = kh+9) needed from kh+2 onward
        const bool doStage = (kh <= KS - 3);
        const int stRin = r0 - PAD + kh + 9;
        int4 stg0 = {0, 0, 0, 0}, stg1 = {0, 0, 0, 0};
        if (doStage) {
            if (t < RCHK) {
                int tc = t / CPP, kc = t - tc * CPP;
                int cin = tc - PAD;
                if (stRin >= 0 && stRin < 32 && cin >= 0 && cin < 32)
                    stg0 = *(const int4*)(sIn + (size_t)(srcPx + stRin * 32 + cin) * CHS + kc * 8);
            }
            if constexpr (RCHK > 512) {
                int e2 = t + 512;
                if (e2 < RCHK) {
                    int tc = e2 / CPP, kc = e2 - tc * CPP;
                    int cin = tc - PAD;
                    if (stRin >= 0 && stRin < 32 && cin >= 0 && cin < 32)
                        stg1 = *(const int4*)(sIn + (size_t)(srcPx + stRin * 32 + cin) * CHS + kc * 8);
                }
            }
        }

        if constexpr (NCH == 1) {
            __builtin_amdgcn_s_setprio(1);
            #pragma unroll
            for (int fm = 0; fm < 8; ++fm) {
                bf16x8 af = *(const bf16x8*)(Atile + aB[fm]);
                #pragma unroll
                for (int fn = 0; fn < NFN; ++fn)
                    acc[fm][fn] = __builtin_amdgcn_mfma_f32_16x16x32_bf16(af, b0[fn], acc[fm][fn], 0, 0, 0);
            }
            __builtin_amdgcn_s_setprio(0);
            if (kh < KS - 1) {
                #pragma unroll
                for (int fn = 0; fn < NFN; ++fn)
                    b0[fn] = *(const bf16x8*)(Bp + CHUNKB + nOff[fn]);
            }
            Bp += CHUNKB;
        } else {
            #pragma unroll 1
            for (int c = 0; c < NCH; c += 2) {
                #pragma unroll
                for (int fn = 0; fn < NFN; ++fn)
                    b1[fn] = *(const bf16x8*)(Bp + (size_t)(c + 1) * CHUNKB + nOff[fn]);
                __builtin_amdgcn_s_setprio(1);
                #pragma unroll
                for (int fm = 0; fm < 8; ++fm) {
                    bf16x8 af = *(const bf16x8*)(Atile + aB[fm] + c * 32);
                    #pragma unroll
                    for (int fn = 0; fn < NFN; ++fn)
                        acc[fm][fn] = __builtin_amdgcn_mfma_f32_16x16x32_bf16(af, b0[fn], acc[fm][fn], 0, 0, 0);
                }
                __builtin_amdgcn_s_setprio(0);
                if (!(kh == KS - 1 && c + 2 >= NCH)) {
                    // flat: rolls into next kh's chunk 0 automatically
                    #pragma unroll
                    for (int fn = 0; fn < NFN; ++fn)
                        b0[fn] = *(const bf16x8*)(Bp + (size_t)(c + 2) * CHUNKB + nOff[fn]);
                }
                __builtin_amdgcn_s_setprio(1);
                #pragma unroll
                for (int fm = 0; fm < 8; ++fm) {
                    bf16x8 af = *(const bf16x8*)(Atile + aB[fm] + (c + 1) * 32);
                    #pragma unroll
                    for (int fn = 0; fn < NFN; ++fn)
                        acc[fm][fn] = __builtin_amdgcn_mfma_f32_16x16x32_bf16(af, b1[fn], acc[fm][fn], 0, 0, 0);
                }
                __builtin_amdgcn_s_setprio(0);
            }
            Bp += (size_t)NCH * CHUNKB;
        }

        // all reads of this kh done -> barrier, then write-late into slot kh
        __syncthreads();
        if (doStage) {
            if (t < RCHK) {
                int tc = t / CPP, kc = t - tc * CPP;
                *(int4*)(Atile + (kh * TCX + tc) * CHS + kc * 8) = stg0;
            }
            if constexpr (RCHK > 512) {
                int e2 = t + 512;
                if (e2 < RCHK) {
                    int tc = e2 / CPP, kc = e2 - tc * CPP;
                    *(int4*)(Atile + (kh * TCX + tc) * CHS + kc * 8) = stg1;
                }
            }
        }
        // slot kh is not read again until kh+2; the kh+1 barrier orders it
    }

    // ---------------- epilogue: bias + relu + store + DCT reduction ----------------
    float cwv[2][4];
    #pragma unroll
    for (int half = 0; half < 2; ++half)
        #pragma unroll
        for (int r = 0; r < 4; ++r)
            cwv[half][r] = cosf(PI_F * (half * 16 + kb * 4 + r + 0.5f) / 32.f);

    #pragma unroll
    for (int fn = 0; fn < NFN; ++fn) {
        int n = nIdx[fn];
        float bv = bias[i * COUT + n];
        float s0 = 0.f, s1 = 0.f;
        #pragma unroll
        for (int fm = 0; fm < 8; ++fm) {
            int imgrow = wm * 4 + (fm >> 1);
            int half = fm & 1;
            #pragma unroll
            for (int r = 0; r < 4; ++r) {
                float v = fmaxf(acc[fm][fn][r] + bv, 0.f);
                if constexpr (CHS_OUT > 0) {
                    int col = half * 16 + kb * 4 + r;
                    int R = r0 + imgrow;
                    sOut[(size_t)(pairPx + R * 32 + col) * CHS_OUT + n] = f2bf(v);
                }
                s0 += v;
                s1 += v * cwv[half][r];
            }
        }
        s0 += __shfl_xor(s0, 16); s1 += __shfl_xor(s1, 16);
        s0 += __shfl_xor(s0, 32); s1 += __shfl_xor(s1, 32);
        if (kb == 0) {
            int ch = i * 448 + FOFF + n;
            atomicAdd(&sums[((size_t)b * 3584 + ch) * 2 + 0], s0);
            atomicAdd(&sums[((size_t)b * 3584 + ch) * 2 + 1], s1);
        }
    }
}

// ---------------- head: LN stats (16 blocks) + parallel GEMV (960 blocks) ----------------
__global__ __launch_bounds__(256) void ln_stats(const float* __restrict__ sums,
                                                float* __restrict__ stats) {
    __shared__ float red[8];
    const int b = blockIdx.x;
    const int t = threadIdx.x, lane = t & 63, wv = t >> 6;
    const float* S = sums + (size_t)b * 7168;
    float ls = 0.f, lq = 0.f;
    for (int f = t; f < 7168; f += 256) { float v = S[f]; ls += v; lq += v * v; }
    for (int m = 1; m < 64; m <<= 1) { ls += __shfl_xor(ls, m); lq += __shfl_xor(lq, m); }
    if (lane == 0) { red[wv] = ls; red[4 + wv] = lq; }
    __syncthreads();
    if (t == 0) {
        float ts = red[0] + red[1] + red[2] + red[3];
        float tq = red[4] + red[5] + red[6] + red[7];
        float mu  = ts * (1.f / 7168.f);
        float var = tq * (1.f / 7168.f) - mu * mu;
        stats[b * 2 + 0] = mu;
        stats[b * 2 + 1] = rsqrtf(var + 1e-5f);
    }
}

__global__ __launch_bounds__(256) void head_gemv(
    const float* __restrict__ sums,   // [16][7168]
    const float* __restrict__ stats,  // [16][2]
    const float* __restrict__ Wg, const float* __restrict__ bg,
    const float* __restrict__ gamma, const float* __restrict__ beta,
    const float* __restrict__ Wd, const float* __restrict__ bd,
    float* __restrict__ out)          // [960 gap][960 dct]
{
    __shared__ float red[8];
    const int n = blockIdx.x % 60;
    const int b = blockIdx.x / 60;
    const int t = threadIdx.x, lane = t & 63, wv = t >> 6;
    const float* S  = sums + (size_t)b * 7168;
    const float mu  = stats[b * 2 + 0];
    const float inv = stats[b * 2 + 1];

    const float* wd = Wd + (size_t)n * 7168;
    float accd = 0.f;
    for (int f = t; f < 7168; f += 256) {
        float v = (S[f] - mu) * inv * gamma[f] + beta[f];
        accd = fmaf(v, wd[f], accd);
    }
    const float* wg = Wg + (size_t)n * 3584;
    float accg = 0.f;
    for (int ch = t; ch < 3584; ch += 256)
        accg = fmaf(S[2 * ch], wg[ch], accg);

    for (int m = 1; m < 64; m <<= 1) { accg += __shfl_xor(accg, m); accd += __shfl_xor(accd, m); }
    if (lane == 0) { red[wv] = accg; red[4 + wv] = accd; }
    __syncthreads();
    if (t == 0) {
        float g = red[0] + red[1] + red[2] + red[3];
        float d = red[4] + red[5] + red[6] + red[7];
        out[b * 60 + n]       = g * (1.f / 1024.f) + bg[n];
        out[960 + b * 60 + n] = d + bd[n];
    }
}

extern "C" void kernel_launch(void* const* d_in, const int* in_sizes, int n_in,
                              void* d_out, int out_size, void* d_ws, size_t ws_size,
                              hipStream_t stream)
{
    const float* x     = (const float*)d_in[0];
    const float* w3    = (const float*)d_in[1];
    const float* b3    = (const float*)d_in[2];
    const float* w5    = (const float*)d_in[3];
    const float* b5    = (const float*)d_in[4];
    const float* w7    = (const float*)d_in[5];
    const float* b7    = (const float*)d_in[6];
    const float* Wg    = (const float*)d_in[7];
    const float* bg    = (const float*)d_in[8];
    const float* gamma = (const float*)d_in[9];
    const float* beta  = (const float*)d_in[10];
    const float* Wd    = (const float*)d_in[11];
    const float* bd    = (const float*)d_in[12];
    float* out = (float*)d_out;

    // workspace layout (bytes)
    char* p = (char*)d_ws;
    float* sums  = (float*)p;             p += 458752;      // 16*3584*2 f32
    float* stats = (float*)p;             p += 128;         // 16*2 f32
    short* s1in = (short*)p;              p += 1048576;     // [64][1024][8]    bf16
    short* s2in = (short*)p;              p += 18874368;    // [128][1024][72]  bf16
    short* s3in = (short*)p;              p += 35651584;    // [128][1024][136] bf16
    short* Bw3  = (short*)p;              p += 98304;       // [8][3][1][64][32]
    short* Bw5  = (short*)p;              p += 3932160;     // [8][5][12][128][32]
    short* Bw7  = (short*)p;              p += 27525120;    // [8][7][30][256][32]

    hipMemsetAsync(sums, 0, 458752, stream);
    prep_s1in<<<dim3(256), dim3(256), 0, stream>>>(x, s1in);
    prep_sx<<<dim3(512), dim3(256), 0, stream>>>(x, s2in, 72, 64);
    prep_sx<<<dim3(512), dim3(256), 0, stream>>>(x, s3in, 136, 128);
    wprep_d<3, 8, 4, 64, 1><<<dim3(24), dim3(256), 0, stream>>>(w3, Bw3);
    wprep_d<5, 72, 68, 128, 12><<<dim3(960), dim3(256), 0, stream>>>(w5, Bw5);
    wprep_d<7, 136, 132, 256, 30><<<dim3(6720), dim3(256), 0, stream>>>(w7, Bw7);

    conv_hk<3, 8, 64, 72, 0, true><<<dim3(512), dim3(512), 0, stream>>>(s1in, s2in, Bw3, b3, sums);
    conv_hk<5, 72, 128, 136, 64, false><<<dim3(512), dim3(512), 0, stream>>>(s2in, s3in, Bw5, b5, sums);
    conv_hk<7, 136, 256, 0, 192, false><<<dim3(512), dim3(512), 0, stream>>>(s3in, nullptr, Bw7, b7, sums);

    ln_stats<<<dim3(16), dim3(256), 0, stream>>>(sums, stats);
    head_gemv<<<dim3(960), dim3(256), 0, stream>>>(sums, stats, Wg, bg, gamma, beta, Wd, bd, out);
}